// Round 15
// baseline (180.714 us; speedup 1.0000x reference)
//
#include <hip/hip_runtime.h>
#include <math.h>

// Problem constants
#define B_  4
#define S_  2048
#define D_  768
#define H_  12
#define DK_ 64
#define M_  (B_ * S_)   // 8192 rows for projection GEMMs
#define NBH_ (B_ * H_)  // 48 (b,h) pairs

typedef float f32x4 __attribute__((ext_vector_type(4)));
typedef float f32x16 __attribute__((ext_vector_type(16)));
typedef __bf16 bf16x8 __attribute__((ext_vector_type(8)));
typedef unsigned u32x4v __attribute__((ext_vector_type(4)));

#if __has_builtin(__builtin_amdgcn_exp2f)
#define EXP2(x) __builtin_amdgcn_exp2f(x)
#else
#define EXP2(x) exp2f(x)
#endif

// fp32 -> bf16 round-to-nearest-even (scalar)
static __device__ __forceinline__ unsigned short f2bf(float f) {
    unsigned u = __builtin_bit_cast(unsigned, f);
    u += 0x7fffu + ((u >> 16) & 1u);
    return (unsigned short)(u >> 16);
}

// pack two f32 -> one u32 of two bf16 (RNE), lo in bits 0-15
static __device__ __forceinline__ unsigned cvt_pk_bf16(float lo, float hi) {
    unsigned r;
    asm("v_cvt_pk_bf16_f32 %0, %1, %2" : "=v"(r) : "v"(lo), "v"(hi));
    return r;
}

// async global->LDS DMA, 16B per lane; LDS dest = wave-uniform base + lane*16
static __device__ __forceinline__ void gload_lds16(const void* g, void* l) {
    __builtin_amdgcn_global_load_lds(
        (const __attribute__((address_space(1))) void*)g,
        (__attribute__((address_space(3))) void*)l, 16, 0, 0);
}

// ---------------- fp32 -> bf16 pre-swizzled convert pass (merged) ---------
// Layout: row-major (rows x 768); within each 32-elem (64B) k-group the four
// 8-elem slots are permuted: stored_slot = slot ^ (row & 3). The GEMM's
// linear global_load_lds image then equals the swizzled LDS image.
// blockIdx.y: 0-2 = activations (M_ rows), 3-6 = weights (D_ rows).
__global__ __launch_bounds__(256) void cvt_all(
    const float* __restrict__ q, const float* __restrict__ k,
    const float* __restrict__ v,
    const float* __restrict__ wq, const float* __restrict__ wk,
    const float* __restrict__ wv, const float* __restrict__ wo,
    unsigned short* __restrict__ q16, unsigned short* __restrict__ k16,
    unsigned short* __restrict__ v16,
    unsigned short* __restrict__ wq16, unsigned short* __restrict__ wk16,
    unsigned short* __restrict__ wv16, unsigned short* __restrict__ wo16)
{
    const int z = blockIdx.y;
    const float* src =
        (z == 0) ? q : (z == 1) ? k : (z == 2) ? v :
        (z == 3) ? wq : (z == 4) ? wk : (z == 5) ? wv : wo;
    unsigned short* dst =
        (z == 0) ? q16 : (z == 1) ? k16 : (z == 2) ? v16 :
        (z == 3) ? wq16 : (z == 4) ? wk16 : (z == 5) ? wv16 : wo16;
    const int NG = ((z < 3) ? M_ : D_) * 96;   // 8-elem granules
    for (int g = blockIdx.x * 256 + threadIdx.x; g < NG; g += gridDim.x * 256) {
        int r = g / 96, c8 = g - r * 96;
        int kt = c8 >> 2, sl = c8 & 3;
        const float* sp = src + (size_t)r * D_ + kt * 32 + sl * 8;
        float4 a = *(const float4*)sp;
        float4 b = *(const float4*)(sp + 4);
        u32x4v o;
        o.x = cvt_pk_bf16(a.x, a.y); o.y = cvt_pk_bf16(a.z, a.w);
        o.z = cvt_pk_bf16(b.x, b.y); o.w = cvt_pk_bf16(b.z, b.w);
        *(u32x4v*)(dst + (size_t)r * D_ + kt * 32 + ((sl ^ (r & 3)) << 3)) = o;
    }
}

// ---------------- bf16 DMA GEMM: out = A @ B^T + bias --------------------
// A16/B16: bf16 pre-swizzled. Staging = global_load_lds DMA, double-buffered,
// COMPILE-TIME buffer index only (runtime index miscompiles — R12 lesson).
// mode 0: bf16 out, (B,H,S,DK), scaled by oscale      (Q; scale 0.125*log2e)
// mode 3: bf16 out, (B,H,S,DK), K-slot-swizzled       (K; attn DMA layout)
// mode 2: bf16 out, V^T (B,H,DK,S), s-slot-swizzled   (V; attn DMA layout)
// mode 1: fp32 out, plain (M_, D_)                    (final output)
static __device__ __forceinline__ void gemm_body_dma(
    const unsigned short* __restrict__ A16, const unsigned short* __restrict__ B16,
    const float* __restrict__ bias, void* __restrict__ outp, const int mode,
    const float oscale)
{
    __shared__ __align__(16) unsigned short As[2][128 * 32];
    __shared__ __align__(16) unsigned short Bs[2][128 * 32];

    const int t  = threadIdx.x;
    const int l  = t & 63;
    const int w  = t >> 6;
    const int lr = l & 15;
    const int lg = l >> 4;
    const int wm = w >> 1;
    const int wn = w & 1;
    const int m0 = blockIdx.x * 128;
    const int n0 = blockIdx.y * 128;

    // DMA geometry: wave w stages rows 32w..32w+31 (2 calls of 16 rows each;
    // lane l -> row l>>2, slot l&3, 16B). LDS image = stored layout verbatim.
    const unsigned short* adma = A16 + (size_t)(m0 + 32 * w + (l >> 2)) * D_ + (l & 3) * 8;
    const unsigned short* bdma = B16 + (size_t)(n0 + 32 * w + (l >> 2)) * D_ + (l & 3) * 8;

#define GSTAGE(K0, NB) do { \
        gload_lds16(adma + (K0),           &As[NB][(32 * w) * 32]); \
        gload_lds16(adma + (K0) + 16 * D_, &As[NB][(32 * w + 16) * 32]); \
        gload_lds16(bdma + (K0),           &Bs[NB][(32 * w) * 32]); \
        gload_lds16(bdma + (K0) + 16 * D_, &Bs[NB][(32 * w + 16) * 32]); \
    } while (0)

    f32x4 acc[4][4];
#pragma unroll
    for (int mi = 0; mi < 4; mi++)
#pragma unroll
        for (int ni = 0; ni < 4; ni++) acc[mi][ni] = (f32x4){0.f, 0.f, 0.f, 0.f};

    const int fsw = lr & 3;   // read-side swizzle: row&3 == lr&3 for frag rows

    GSTAGE(0, 0);
    __syncthreads();

    for (int kt = 0; kt < 24; kt++) {
        const int cur = kt & 1;
        if (kt < 23) {
            if (cur) GSTAGE((kt + 1) * 32, 0);
            else     GSTAGE((kt + 1) * 32, 1);
        }

        bf16x8 af[4], bfr[4];
#pragma unroll
        for (int mi = 0; mi < 4; mi++) {
            int row = wm * 64 + mi * 16 + lr;
            af[mi] = *(const bf16x8*)&As[cur][row * 32 + ((lg ^ fsw) << 3)];
        }
#pragma unroll
        for (int ni = 0; ni < 4; ni++) {
            int row = wn * 64 + ni * 16 + lr;
            bfr[ni] = *(const bf16x8*)&Bs[cur][row * 32 + ((lg ^ fsw) << 3)];
        }
#pragma unroll
        for (int mi = 0; mi < 4; mi++)
#pragma unroll
            for (int ni = 0; ni < 4; ni++)
                acc[mi][ni] = __builtin_amdgcn_mfma_f32_16x16x32_bf16(
                    af[mi], bfr[ni], acc[mi][ni], 0, 0, 0);

        __syncthreads();   // drains DMA (vmcnt) + orders buffer reuse
    }
#undef GSTAGE

    const int mrow0 = m0 + wm * 64;
    const int ncol0 = n0 + wn * 64;
    if (mode == 1) {
        float* out = (float*)outp;
#pragma unroll
        for (int mi = 0; mi < 4; mi++)
#pragma unroll
            for (int ni = 0; ni < 4; ni++) {
                int n = ncol0 + ni * 16 + lr;
                float bv = bias[n];
#pragma unroll
                for (int j = 0; j < 4; j++) {
                    int m = mrow0 + mi * 16 + 4 * lg + j;
                    out[(size_t)m * D_ + n] = acc[mi][ni][j] + bv;
                }
            }
    } else if (mode == 2) {
        // V^T (B,H,DK,S), s-slot swizzled within each 64-key tile:
        // stored col s' = (s&~63) | ((((s>>3)&7) ^ (dk&7))<<3) | (s&7)
        unsigned short* out = (unsigned short*)outp;
#pragma unroll
        for (int mi = 0; mi < 4; mi++)
#pragma unroll
            for (int ni = 0; ni < 4; ni++) {
                int n = ncol0 + ni * 16 + lr;
                int h = n >> 6, dk = n & 63;
                float bv = bias[n];
                int m = mrow0 + mi * 16 + 4 * lg;    // s, s%4==0
                int b = m >> 11, s = m & (S_ - 1);
                int slotp = ((s >> 3) & 7) ^ (dk & 7);
                int ssw = (s & ~63) | (slotp << 3) | (s & 7);
                uint2 o;
                o.x = cvt_pk_bf16(acc[mi][ni][0] + bv, acc[mi][ni][1] + bv);
                o.y = cvt_pk_bf16(acc[mi][ni][2] + bv, acc[mi][ni][3] + bv);
                *(uint2*)&out[((size_t)(b * H_ + h) * DK_ + dk) * S_ + ssw] = o;
            }
    } else {
        // mode 0 (Q, plain) / mode 3 (K, dk-slot swizzled per row)
        unsigned short* out = (unsigned short*)outp;
#pragma unroll
        for (int mi = 0; mi < 4; mi++)
#pragma unroll
            for (int ni = 0; ni < 4; ni++) {
                int n = ncol0 + ni * 16 + lr;
                int h = n >> 6, dk = n & 63;
                float bv = bias[n];
#pragma unroll
                for (int j = 0; j < 4; j++) {
                    int m = mrow0 + mi * 16 + 4 * lg + j;
                    int b = m >> 11, s = m & (S_ - 1);
                    int dko = (mode == 3)
                        ? ((dk & 7) | ((((dk >> 3) ^ (s & 7))) << 3)) : dk;
                    out[((size_t)(b * H_ + h) * S_ + s) * DK_ + dko] =
                        f2bf((acc[mi][ni][j] + bv) * oscale);
                }
            }
    }
}

__global__ __launch_bounds__(256) void gemm_qkv(
    const unsigned short* __restrict__ q16, const unsigned short* __restrict__ k16,
    const unsigned short* __restrict__ v16,
    const unsigned short* __restrict__ wq16, const unsigned short* __restrict__ wk16,
    const unsigned short* __restrict__ wv16,
    const float* __restrict__ bq, const float* __restrict__ bk,
    const float* __restrict__ bv,
    unsigned short* __restrict__ Qb, unsigned short* __restrict__ Kb,
    unsigned short* __restrict__ VT)
{
    const int z = blockIdx.z;
    const unsigned short* A = (z == 0) ? q16 : (z == 1) ? k16 : v16;
    const unsigned short* W = (z == 0) ? wq16 : (z == 1) ? wk16 : wv16;
    const float* bias = (z == 0) ? bq : (z == 1) ? bk : bv;
    void* out = (z == 0) ? (void*)Qb : (z == 1) ? (void*)Kb : (void*)VT;
    const int mode = (z == 0) ? 0 : (z == 1) ? 3 : 2;
    // Q pre-scale: (1/sqrt(DK)) * log2(e) so softmax uses exp2 directly
    const float osc = (z == 0) ? 0.18033688011112042f : 1.0f;
    gemm_body_dma(A, W, bias, out, mode, osc);
}

// final output projection: A = attn's bf16 pre-swizzled Xb16, fp32 out
__global__ __launch_bounds__(256) void gemm_o(
    const unsigned short* __restrict__ X16, const unsigned short* __restrict__ wo16,
    const float* __restrict__ bo, float* __restrict__ out)
{
    gemm_body_dma(X16, wo16, bo, (void*)out, 1, 1.0f);
}

// ---------------- Swapped-operand 32x32 MFMA flash attention --------------
// Qb (PRE-SCALED by log2e/8) plain; Kb slot-swizzled; VTb s-slot-swizzled.
// Output: Xb16 bf16 (B,S,D) merged heads, slot-swizzled for gemm_o's DMA.
// R15: MASK REGISTER-PREFETCH — tile t consumes mask regs loaded at t-1
// (retired by the barrier drain => zero VMEM wait at tile top). Previously
// the mask loads sat AFTER the 4 DMAs in the wave's FIFO VMEM queue and were
// consumed immediately -> waiting for them forced the whole next-tile DMA
// batch to drain at the top of every tile (prefetch distance collapsed to 0).
__global__ __launch_bounds__(256) void attn_mfma(
    const unsigned short* __restrict__ Qb, const unsigned short* __restrict__ Kb,
    const unsigned short* __restrict__ VTb, const int* __restrict__ mask,
    unsigned short* __restrict__ Xb16)
{
    __shared__ __align__(16) unsigned short Ks[2][64 * 64];
    __shared__ __align__(16) unsigned short Vs[2][64 * 64];

    const int tid = threadIdx.x;
    const int w  = tid >> 6;
    const int l  = tid & 63;
    const int q  = l & 31;
    const int hl = l >> 5;

    const int bh = blockIdx.x % NBH_;
    const int qt = blockIdx.x / NBH_;
    const int b  = bh / H_;
    const int hh = bh - b * H_;
    const int q0 = qt * 128 + w * 32;

    const unsigned short* qp = Qb + ((size_t)bh * S_ + q0 + q) * DK_;
    bf16x8 qf[4];
#pragma unroll
    for (int c = 0; c < 4; c++)
        qf[c] = *(const bf16x8*)(qp + c * 16 + hl * 8);

    const unsigned qext_sel = (hl == 0) ? 0x00003F80u : 0u;   // bf16 1.0 elem0
    const unsigned bias_sel = (hl == 0) ? 0x0000C480u : 0u;   // bf16 -1024 elem0
    u32x4v qe; qe.x = qext_sel; qe.y = 0u; qe.z = 0u; qe.w = 0u;
    const bf16x8 qf_ext = __builtin_bit_cast(bf16x8, qe);
    u32x4v on; on.x = on.y = on.z = on.w = 0x3F803F80u;       // bf16 1.0 pairs
    const bf16x8 vOnes = __builtin_bit_cast(bf16x8, on);

    f32x16 acc0, acc1, accl;
#pragma unroll
    for (int i = 0; i < 16; i++) { acc0[i] = 0.f; acc1[i] = 0.f; accl[i] = 0.f; }

    const unsigned short* kbase = Kb + (size_t)bh * S_ * DK_;
    const unsigned short* vbase = VTb + (size_t)bh * DK_ * S_;
    const int* mbase = mask + b * S_;

    const unsigned short* kdma = kbase + (16 * w) * DK_ + l * 8;
    const unsigned short* vdma0 = vbase + (size_t)(16 * w + (l >> 3)) * S_ + (l & 7) * 8;
    const unsigned short* vdma1 = vdma0 + (size_t)8 * S_;

#define STAGE_DMA(J0, NB) do { \
        gload_lds16(kdma + (size_t)(J0) * DK_,            &Ks[NB][(16 * w) * 64]); \
        gload_lds16(kdma + (size_t)(J0) * DK_ + 8 * DK_,  &Ks[NB][(16 * w + 8) * 64]); \
        gload_lds16(vdma0 + (J0),                         &Vs[NB][(16 * w) * 64]); \
        gload_lds16(vdma1 + (J0),                         &Vs[NB][(16 * w + 8) * 64]); \
    } while (0)

    STAGE_DMA(0, 0);
    // prologue: tile-0 masks into registers (drained by the barrier below)
    int mv0 = mbase[q];
    int mv1 = mbase[32 + q];
    __syncthreads();

    const int fsw = (q & 7) << 3;
    const int kr0o = q * 64;
    const int kr1o = (32 + q) * 64;

    for (int tt = 0; tt < 32; tt++) {
        const int j0  = tt * 64;
        const int cur = tt & 1;

        if (tt < 31) {
            if (cur) STAGE_DMA(j0 + 64, 0); else STAGE_DMA(j0 + 64, 1);
        }

        // consume the PREFETCHED mask registers (zero VMEM wait here)
        const int mc0 = mv0, mc1 = mv1;
        // prefetch next tile's masks; consumed next iteration (post-barrier)
        {
            const int jn = (tt < 31) ? (j0 + 64) : 0;   // wrap: dead prefetch
            mv0 = mbase[jn + q];
            mv1 = mbase[jn + 32 + q];
        }

        u32x4v bw0; bw0.x = (mc0 == 0) ? bias_sel : 0u; bw0.y = 0u; bw0.z = 0u; bw0.w = 0u;
        u32x4v bw1; bw1.x = (mc1 == 0) ? bias_sel : 0u; bw1.y = 0u; bw1.z = 0u; bw1.w = 0u;
        bf16x8 kExt0 = __builtin_bit_cast(bf16x8, bw0);
        bf16x8 kExt1 = __builtin_bit_cast(bf16x8, bw1);

        f32x16 s0, s1;
#pragma unroll
        for (int i = 0; i < 16; i++) { s0[i] = 0.f; s1[i] = 0.f; }
        s0 = __builtin_amdgcn_mfma_f32_32x32x16_bf16(kExt0, qf_ext, s0, 0, 0, 0);
        s1 = __builtin_amdgcn_mfma_f32_32x32x16_bf16(kExt1, qf_ext, s1, 0, 0, 0);
#pragma unroll
        for (int c = 0; c < 4; c++) {
            bf16x8 k0 = *(const bf16x8*)&Ks[cur][kr0o + ((c * 16 + hl * 8) ^ fsw)];
            bf16x8 k1 = *(const bf16x8*)&Ks[cur][kr1o + ((c * 16 + hl * 8) ^ fsw)];
            s0 = __builtin_amdgcn_mfma_f32_32x32x16_bf16(k0, qf[c], s0, 0, 0, 0);
            s1 = __builtin_amdgcn_mfma_f32_32x32x16_bf16(k1, qf[c], s1, 0, 0, 0);
        }

#pragma unroll
        for (int r = 0; r < 16; r++) s0[r] = EXP2(s0[r]);
#pragma unroll
        for (int r = 0; r < 16; r++) s1[r] = EXP2(s1[r]);

#define SVAL(CP, I) (((CP) >> 1) ? s1[I] : s0[I])
        bf16x8 pb[4];
#pragma unroll
        for (int cp = 0; cp < 4; cp++) {
            const int e0 = 8 * (cp & 1);
            unsigned lo0 = cvt_pk_bf16(SVAL(cp, e0 + 0), SVAL(cp, e0 + 1));
            unsigned hi0 = cvt_pk_bf16(SVAL(cp, e0 + 2), SVAL(cp, e0 + 3));
            unsigned lo1 = cvt_pk_bf16(SVAL(cp, e0 + 4), SVAL(cp, e0 + 5));
            unsigned hi1 = cvt_pk_bf16(SVAL(cp, e0 + 6), SVAL(cp, e0 + 7));
            asm("v_permlane32_swap_b32 %0, %1" : "+v"(lo0), "+v"(lo1));
            asm("v_permlane32_swap_b32 %0, %1" : "+v"(hi0), "+v"(hi1));
            u32x4v pw;
            pw.x = lo0; pw.y = hi0; pw.z = lo1; pw.w = hi1;
            pb[cp] = __builtin_bit_cast(bf16x8, pw);
        }
#undef SVAL

#pragma unroll
        for (int cp = 0; cp < 4; cp++) {
            bf16x8 v0 = *(const bf16x8*)&Vs[cur][kr0o + ((cp * 16 + hl * 8) ^ fsw)];
            bf16x8 v1 = *(const bf16x8*)&Vs[cur][kr1o + ((cp * 16 + hl * 8) ^ fsw)];
            acc0 = __builtin_amdgcn_mfma_f32_32x32x16_bf16(v0, pb[cp], acc0, 0, 0, 0);
            acc1 = __builtin_amdgcn_mfma_f32_32x32x16_bf16(v1, pb[cp], acc1, 0, 0, 0);
            accl = __builtin_amdgcn_mfma_f32_32x32x16_bf16(vOnes, pb[cp], accl, 0, 0, 0);
        }

        __syncthreads();
    }
#undef STAGE_DMA

    // ---- epilogue: normalize, write bf16 pre-swizzled (B,S,D) ----
    float inv = 1.f / accl[0];
    unsigned short* ob = Xb16 + ((size_t)b * S_ + q0 + q) * D_ + hh * DK_;
    const int rsw = q & 3;
#pragma unroll
    for (int b2 = 0; b2 < 4; b2++) {
        uint2 o0;
        o0.x = cvt_pk_bf16(acc0[4 * b2 + 0] * inv, acc0[4 * b2 + 1] * inv);
        o0.y = cvt_pk_bf16(acc0[4 * b2 + 2] * inv, acc0[4 * b2 + 3] * inv);
        *(uint2*)(ob + (((b2 ^ rsw) << 3) + 4 * hl)) = o0;
        uint2 o1;
        o1.x = cvt_pk_bf16(acc1[4 * b2 + 0] * inv, acc1[4 * b2 + 1] * inv);
        o1.y = cvt_pk_bf16(acc1[4 * b2 + 2] * inv, acc1[4 * b2 + 3] * inv);
        *(uint2*)(ob + 32 + (((b2 ^ rsw) << 3) + 4 * hl)) = o1;
    }
}

// ---------------- host launcher ----------------
extern "C" void kernel_launch(void* const* d_in, const int* in_sizes, int n_in,
                              void* d_out, int out_size, void* d_ws, size_t ws_size,
                              hipStream_t stream) {
    (void)in_sizes; (void)n_in; (void)out_size; (void)ws_size;

    const float* query = (const float*)d_in[0];
    const float* key_  = (const float*)d_in[1];
    const float* value = (const float*)d_in[2];
    const int*   mask  = (const int*)d_in[3];
    const float* Wq = (const float*)d_in[4];  const float* bq = (const float*)d_in[5];
    const float* Wk = (const float*)d_in[6];  const float* bk = (const float*)d_in[7];
    const float* Wv = (const float*)d_in[8];  const float* bv = (const float*)d_in[9];
    const float* Wo = (const float*)d_in[10]; const float* bo = (const float*)d_in[11];
    float* out = (float*)d_out;

    const size_t MD = (size_t)M_ * D_;     // 6,291,456
    const size_t DD = (size_t)D_ * D_;     // 589,824
    unsigned short* q16  = (unsigned short*)d_ws;
    unsigned short* k16  = q16 + MD;
    unsigned short* v16  = k16 + MD;
    unsigned short* Qb   = v16 + MD;
    unsigned short* Kb   = Qb + MD;
    unsigned short* VT   = Kb + MD;
    unsigned short* Xb16 = VT + MD;
    unsigned short* Wq16 = Xb16 + MD;
    unsigned short* Wk16 = Wq16 + DD;
    unsigned short* Wv16 = Wk16 + DD;
    unsigned short* Wo16 = Wv16 + DD;

    cvt_all<<<dim3(1024, 7), 256, 0, stream>>>(
        query, key_, value, Wq, Wk, Wv, Wo,
        q16, k16, v16, Wq16, Wk16, Wv16, Wo16);

    gemm_qkv<<<dim3(M_ / 128, D_ / 128, 3), 256, 0, stream>>>(
        q16, k16, v16, Wq16, Wk16, Wv16, bq, bk, bv, Qb, Kb, VT);

    attn_mfma<<<dim3((S_ / 128) * NBH_), 256, 0, stream>>>(Qb, Kb, VT, mask, Xb16);

    gemm_o<<<dim3(M_ / 128, D_ / 128), 256, 0, stream>>>(Xb16, Wo16, bo, out);
}

// Round 16
// 173.984 us; speedup vs baseline: 1.0387x; 1.0387x over previous
//
#include <hip/hip_runtime.h>
#include <math.h>

// Problem constants
#define B_  4
#define S_  2048
#define D_  768
#define H_  12
#define DK_ 64
#define M_  (B_ * S_)   // 8192 rows for projection GEMMs
#define NBH_ (B_ * H_)  // 48 (b,h) pairs

typedef float f32x4 __attribute__((ext_vector_type(4)));
typedef float f32x16 __attribute__((ext_vector_type(16)));
typedef __bf16 bf16x8 __attribute__((ext_vector_type(8)));
typedef unsigned u32x4v __attribute__((ext_vector_type(4)));

#if __has_builtin(__builtin_amdgcn_exp2f)
#define EXP2(x) __builtin_amdgcn_exp2f(x)
#else
#define EXP2(x) exp2f(x)
#endif

// fp32 -> bf16 round-to-nearest-even (scalar)
static __device__ __forceinline__ unsigned short f2bf(float f) {
    unsigned u = __builtin_bit_cast(unsigned, f);
    u += 0x7fffu + ((u >> 16) & 1u);
    return (unsigned short)(u >> 16);
}

// pack two f32 -> one u32 of two bf16 (RNE), lo in bits 0-15
static __device__ __forceinline__ unsigned cvt_pk_bf16(float lo, float hi) {
    unsigned r;
    asm("v_cvt_pk_bf16_f32 %0, %1, %2" : "=v"(r) : "v"(lo), "v"(hi));
    return r;
}

// async global->LDS DMA, 16B per lane; LDS dest = wave-uniform base + lane*16
static __device__ __forceinline__ void gload_lds16(const void* g, void* l) {
    __builtin_amdgcn_global_load_lds(
        (const __attribute__((address_space(1))) void*)g,
        (__attribute__((address_space(3))) void*)l, 16, 0, 0);
}

// ---------------- fp32 -> bf16 pre-swizzled convert pass (merged) ---------
// Layout: row-major (rows x 768); within each 32-elem (64B) k-group the four
// 8-elem slots are permuted: stored_slot = slot ^ (row & 3). The GEMM's
// linear global_load_lds image then equals the swizzled LDS image.
// blockIdx.y: 0-2 = activations (M_ rows), 3-6 = weights (D_ rows).
__global__ __launch_bounds__(256) void cvt_all(
    const float* __restrict__ q, const float* __restrict__ k,
    const float* __restrict__ v,
    const float* __restrict__ wq, const float* __restrict__ wk,
    const float* __restrict__ wv, const float* __restrict__ wo,
    unsigned short* __restrict__ q16, unsigned short* __restrict__ k16,
    unsigned short* __restrict__ v16,
    unsigned short* __restrict__ wq16, unsigned short* __restrict__ wk16,
    unsigned short* __restrict__ wv16, unsigned short* __restrict__ wo16)
{
    const int z = blockIdx.y;
    const float* src =
        (z == 0) ? q : (z == 1) ? k : (z == 2) ? v :
        (z == 3) ? wq : (z == 4) ? wk : (z == 5) ? wv : wo;
    unsigned short* dst =
        (z == 0) ? q16 : (z == 1) ? k16 : (z == 2) ? v16 :
        (z == 3) ? wq16 : (z == 4) ? wk16 : (z == 5) ? wv16 : wo16;
    const int NG = ((z < 3) ? M_ : D_) * 96;   // 8-elem granules
    for (int g = blockIdx.x * 256 + threadIdx.x; g < NG; g += gridDim.x * 256) {
        int r = g / 96, c8 = g - r * 96;
        int kt = c8 >> 2, sl = c8 & 3;
        const float* sp = src + (size_t)r * D_ + kt * 32 + sl * 8;
        float4 a = *(const float4*)sp;
        float4 b = *(const float4*)(sp + 4);
        u32x4v o;
        o.x = cvt_pk_bf16(a.x, a.y); o.y = cvt_pk_bf16(a.z, a.w);
        o.z = cvt_pk_bf16(b.x, b.y); o.w = cvt_pk_bf16(b.z, b.w);
        *(u32x4v*)(dst + (size_t)r * D_ + kt * 32 + ((sl ^ (r & 3)) << 3)) = o;
    }
}

// ---------------- bf16 DMA GEMM: out = A @ B^T + bias --------------------
// A16/B16: bf16 pre-swizzled. Staging = global_load_lds DMA, double-buffered,
// COMPILE-TIME buffer index only (runtime index miscompiles — R12 lesson).
// mode 0: bf16 out, (B,H,S,DK), scaled by oscale      (Q; scale 0.125*log2e)
// mode 3: bf16 out, (B,H,S,DK), K-slot-swizzled       (K; attn DMA layout)
// mode 2: bf16 out, V^T (B,H,DK,S), s-slot-swizzled   (V; attn DMA layout)
// mode 1: fp32 out, plain (M_, D_)                    (final output)
static __device__ __forceinline__ void gemm_body_dma(
    const unsigned short* __restrict__ A16, const unsigned short* __restrict__ B16,
    const float* __restrict__ bias, void* __restrict__ outp, const int mode,
    const float oscale)
{
    __shared__ __align__(16) unsigned short As[2][128 * 32];
    __shared__ __align__(16) unsigned short Bs[2][128 * 32];

    const int t  = threadIdx.x;
    const int l  = t & 63;
    const int w  = t >> 6;
    const int lr = l & 15;
    const int lg = l >> 4;
    const int wm = w >> 1;
    const int wn = w & 1;
    const int m0 = blockIdx.x * 128;
    const int n0 = blockIdx.y * 128;

    // DMA geometry: wave w stages rows 32w..32w+31 (2 calls of 16 rows each;
    // lane l -> row l>>2, slot l&3, 16B). LDS image = stored layout verbatim.
    const unsigned short* adma = A16 + (size_t)(m0 + 32 * w + (l >> 2)) * D_ + (l & 3) * 8;
    const unsigned short* bdma = B16 + (size_t)(n0 + 32 * w + (l >> 2)) * D_ + (l & 3) * 8;

#define GSTAGE(K0, NB) do { \
        gload_lds16(adma + (K0),           &As[NB][(32 * w) * 32]); \
        gload_lds16(adma + (K0) + 16 * D_, &As[NB][(32 * w + 16) * 32]); \
        gload_lds16(bdma + (K0),           &Bs[NB][(32 * w) * 32]); \
        gload_lds16(bdma + (K0) + 16 * D_, &Bs[NB][(32 * w + 16) * 32]); \
    } while (0)

    f32x4 acc[4][4];
#pragma unroll
    for (int mi = 0; mi < 4; mi++)
#pragma unroll
        for (int ni = 0; ni < 4; ni++) acc[mi][ni] = (f32x4){0.f, 0.f, 0.f, 0.f};

    const int fsw = lr & 3;   // read-side swizzle: row&3 == lr&3 for frag rows

    GSTAGE(0, 0);
    __syncthreads();

    for (int kt = 0; kt < 24; kt++) {
        const int cur = kt & 1;
        if (kt < 23) {
            if (cur) GSTAGE((kt + 1) * 32, 0);
            else     GSTAGE((kt + 1) * 32, 1);
        }

        bf16x8 af[4], bfr[4];
#pragma unroll
        for (int mi = 0; mi < 4; mi++) {
            int row = wm * 64 + mi * 16 + lr;
            af[mi] = *(const bf16x8*)&As[cur][row * 32 + ((lg ^ fsw) << 3)];
        }
#pragma unroll
        for (int ni = 0; ni < 4; ni++) {
            int row = wn * 64 + ni * 16 + lr;
            bfr[ni] = *(const bf16x8*)&Bs[cur][row * 32 + ((lg ^ fsw) << 3)];
        }
#pragma unroll
        for (int mi = 0; mi < 4; mi++)
#pragma unroll
            for (int ni = 0; ni < 4; ni++)
                acc[mi][ni] = __builtin_amdgcn_mfma_f32_16x16x32_bf16(
                    af[mi], bfr[ni], acc[mi][ni], 0, 0, 0);

        __syncthreads();   // drains DMA (vmcnt) + orders buffer reuse
    }
#undef GSTAGE

    const int mrow0 = m0 + wm * 64;
    const int ncol0 = n0 + wn * 64;
    if (mode == 1) {
        float* out = (float*)outp;
#pragma unroll
        for (int mi = 0; mi < 4; mi++)
#pragma unroll
            for (int ni = 0; ni < 4; ni++) {
                int n = ncol0 + ni * 16 + lr;
                float bv = bias[n];
#pragma unroll
                for (int j = 0; j < 4; j++) {
                    int m = mrow0 + mi * 16 + 4 * lg + j;
                    out[(size_t)m * D_ + n] = acc[mi][ni][j] + bv;
                }
            }
    } else if (mode == 2) {
        // V^T (B,H,DK,S), s-slot swizzled within each 64-key tile:
        // stored col s' = (s&~63) | ((((s>>3)&7) ^ (dk&7))<<3) | (s&7)
        unsigned short* out = (unsigned short*)outp;
#pragma unroll
        for (int mi = 0; mi < 4; mi++)
#pragma unroll
            for (int ni = 0; ni < 4; ni++) {
                int n = ncol0 + ni * 16 + lr;
                int h = n >> 6, dk = n & 63;
                float bv = bias[n];
                int m = mrow0 + mi * 16 + 4 * lg;    // s, s%4==0
                int b = m >> 11, s = m & (S_ - 1);
                int slotp = ((s >> 3) & 7) ^ (dk & 7);
                int ssw = (s & ~63) | (slotp << 3) | (s & 7);
                uint2 o;
                o.x = cvt_pk_bf16(acc[mi][ni][0] + bv, acc[mi][ni][1] + bv);
                o.y = cvt_pk_bf16(acc[mi][ni][2] + bv, acc[mi][ni][3] + bv);
                *(uint2*)&out[((size_t)(b * H_ + h) * DK_ + dk) * S_ + ssw] = o;
            }
    } else {
        // mode 0 (Q, plain) / mode 3 (K, dk-slot swizzled per row)
        unsigned short* out = (unsigned short*)outp;
#pragma unroll
        for (int mi = 0; mi < 4; mi++)
#pragma unroll
            for (int ni = 0; ni < 4; ni++) {
                int n = ncol0 + ni * 16 + lr;
                int h = n >> 6, dk = n & 63;
                float bv = bias[n];
#pragma unroll
                for (int j = 0; j < 4; j++) {
                    int m = mrow0 + mi * 16 + 4 * lg + j;
                    int b = m >> 11, s = m & (S_ - 1);
                    int dko = (mode == 3)
                        ? ((dk & 7) | ((((dk >> 3) ^ (s & 7))) << 3)) : dk;
                    out[((size_t)(b * H_ + h) * S_ + s) * DK_ + dko] =
                        f2bf((acc[mi][ni][j] + bv) * oscale);
                }
            }
    }
}

__global__ __launch_bounds__(256) void gemm_qkv(
    const unsigned short* __restrict__ q16, const unsigned short* __restrict__ k16,
    const unsigned short* __restrict__ v16,
    const unsigned short* __restrict__ wq16, const unsigned short* __restrict__ wk16,
    const unsigned short* __restrict__ wv16,
    const float* __restrict__ bq, const float* __restrict__ bk,
    const float* __restrict__ bv,
    unsigned short* __restrict__ Qb, unsigned short* __restrict__ Kb,
    unsigned short* __restrict__ VT)
{
    const int z = blockIdx.z;
    const unsigned short* A = (z == 0) ? q16 : (z == 1) ? k16 : v16;
    const unsigned short* W = (z == 0) ? wq16 : (z == 1) ? wk16 : wv16;
    const float* bias = (z == 0) ? bq : (z == 1) ? bk : bv;
    void* out = (z == 0) ? (void*)Qb : (z == 1) ? (void*)Kb : (void*)VT;
    const int mode = (z == 0) ? 0 : (z == 1) ? 3 : 2;
    // Q pre-scale: (1/sqrt(DK)) * log2(e) so softmax uses exp2 directly
    const float osc = (z == 0) ? 0.18033688011112042f : 1.0f;
    gemm_body_dma(A, W, bias, out, mode, osc);
}

// final output projection: A = attn's bf16 pre-swizzled Xb16, fp32 out
__global__ __launch_bounds__(256) void gemm_o(
    const unsigned short* __restrict__ X16, const unsigned short* __restrict__ wo16,
    const float* __restrict__ bo, float* __restrict__ out)
{
    gemm_body_dma(X16, wo16, bo, (void*)out, 1, 1.0f);
}

// ---------------- Swapped-operand 32x32 MFMA flash attention --------------
// EXACT R14 kernel (best measured: 82 µs). Qb (PRE-SCALED by log2e/8) plain;
// Kb slot-swizzled; VTb s-slot-swizzled. Output: Xb16 bf16 (B,S,D) merged
// heads, slot-swizzled for gemm_o's DMA. K/V staged via global_load_lds DMA,
// double-buffered (compile-time BUF); exp2-domain softmax; mask folded into
// QK^T; row-sum l via ones-MFMA; permlane32_swap pack; no setprio; mask
// loads inline (compiler schedules them — R15's manual prefetch regressed).
__global__ __launch_bounds__(256) void attn_mfma(
    const unsigned short* __restrict__ Qb, const unsigned short* __restrict__ Kb,
    const unsigned short* __restrict__ VTb, const int* __restrict__ mask,
    unsigned short* __restrict__ Xb16)
{
    __shared__ __align__(16) unsigned short Ks[2][64 * 64];
    __shared__ __align__(16) unsigned short Vs[2][64 * 64];

    const int tid = threadIdx.x;
    const int w  = tid >> 6;
    const int l  = tid & 63;
    const int q  = l & 31;
    const int hl = l >> 5;

    const int bh = blockIdx.x % NBH_;
    const int qt = blockIdx.x / NBH_;
    const int b  = bh / H_;
    const int hh = bh - b * H_;
    const int q0 = qt * 128 + w * 32;

    const unsigned short* qp = Qb + ((size_t)bh * S_ + q0 + q) * DK_;
    bf16x8 qf[4];
#pragma unroll
    for (int c = 0; c < 4; c++)
        qf[c] = *(const bf16x8*)(qp + c * 16 + hl * 8);

    const unsigned qext_sel = (hl == 0) ? 0x00003F80u : 0u;   // bf16 1.0 elem0
    const unsigned bias_sel = (hl == 0) ? 0x0000C480u : 0u;   // bf16 -1024 elem0
    u32x4v qe; qe.x = qext_sel; qe.y = 0u; qe.z = 0u; qe.w = 0u;
    const bf16x8 qf_ext = __builtin_bit_cast(bf16x8, qe);
    u32x4v on; on.x = on.y = on.z = on.w = 0x3F803F80u;       // bf16 1.0 pairs
    const bf16x8 vOnes = __builtin_bit_cast(bf16x8, on);

    f32x16 acc0, acc1, accl;
#pragma unroll
    for (int i = 0; i < 16; i++) { acc0[i] = 0.f; acc1[i] = 0.f; accl[i] = 0.f; }

    const unsigned short* kbase = Kb + (size_t)bh * S_ * DK_;
    const unsigned short* vbase = VTb + (size_t)bh * DK_ * S_;
    const int* mbase = mask + b * S_;

    const unsigned short* kdma = kbase + (16 * w) * DK_ + l * 8;
    const unsigned short* vdma0 = vbase + (size_t)(16 * w + (l >> 3)) * S_ + (l & 7) * 8;
    const unsigned short* vdma1 = vdma0 + (size_t)8 * S_;

#define STAGE_DMA(J0, NB) do { \
        gload_lds16(kdma + (size_t)(J0) * DK_,            &Ks[NB][(16 * w) * 64]); \
        gload_lds16(kdma + (size_t)(J0) * DK_ + 8 * DK_,  &Ks[NB][(16 * w + 8) * 64]); \
        gload_lds16(vdma0 + (J0),                         &Vs[NB][(16 * w) * 64]); \
        gload_lds16(vdma1 + (J0),                         &Vs[NB][(16 * w + 8) * 64]); \
    } while (0)

    STAGE_DMA(0, 0);
    __syncthreads();

    const int fsw = (q & 7) << 3;
    const int kr0o = q * 64;
    const int kr1o = (32 + q) * 64;

    for (int tt = 0; tt < 32; tt++) {
        const int j0  = tt * 64;
        const int cur = tt & 1;

        if (tt < 31) {
            if (cur) STAGE_DMA(j0 + 64, 0); else STAGE_DMA(j0 + 64, 1);
        }

        int mv0 = mbase[j0 + q];
        int mv1 = mbase[j0 + 32 + q];
        u32x4v bw0; bw0.x = (mv0 == 0) ? bias_sel : 0u; bw0.y = 0u; bw0.z = 0u; bw0.w = 0u;
        u32x4v bw1; bw1.x = (mv1 == 0) ? bias_sel : 0u; bw1.y = 0u; bw1.z = 0u; bw1.w = 0u;
        bf16x8 kExt0 = __builtin_bit_cast(bf16x8, bw0);
        bf16x8 kExt1 = __builtin_bit_cast(bf16x8, bw1);

        f32x16 s0, s1;
#pragma unroll
        for (int i = 0; i < 16; i++) { s0[i] = 0.f; s1[i] = 0.f; }
        s0 = __builtin_amdgcn_mfma_f32_32x32x16_bf16(kExt0, qf_ext, s0, 0, 0, 0);
        s1 = __builtin_amdgcn_mfma_f32_32x32x16_bf16(kExt1, qf_ext, s1, 0, 0, 0);
#pragma unroll
        for (int c = 0; c < 4; c++) {
            bf16x8 k0 = *(const bf16x8*)&Ks[cur][kr0o + ((c * 16 + hl * 8) ^ fsw)];
            bf16x8 k1 = *(const bf16x8*)&Ks[cur][kr1o + ((c * 16 + hl * 8) ^ fsw)];
            s0 = __builtin_amdgcn_mfma_f32_32x32x16_bf16(k0, qf[c], s0, 0, 0, 0);
            s1 = __builtin_amdgcn_mfma_f32_32x32x16_bf16(k1, qf[c], s1, 0, 0, 0);
        }

#pragma unroll
        for (int r = 0; r < 16; r++) s0[r] = EXP2(s0[r]);
#pragma unroll
        for (int r = 0; r < 16; r++) s1[r] = EXP2(s1[r]);

#define SVAL(CP, I) (((CP) >> 1) ? s1[I] : s0[I])
        bf16x8 pb[4];
#pragma unroll
        for (int cp = 0; cp < 4; cp++) {
            const int e0 = 8 * (cp & 1);
            unsigned lo0 = cvt_pk_bf16(SVAL(cp, e0 + 0), SVAL(cp, e0 + 1));
            unsigned hi0 = cvt_pk_bf16(SVAL(cp, e0 + 2), SVAL(cp, e0 + 3));
            unsigned lo1 = cvt_pk_bf16(SVAL(cp, e0 + 4), SVAL(cp, e0 + 5));
            unsigned hi1 = cvt_pk_bf16(SVAL(cp, e0 + 6), SVAL(cp, e0 + 7));
            asm("v_permlane32_swap_b32 %0, %1" : "+v"(lo0), "+v"(lo1));
            asm("v_permlane32_swap_b32 %0, %1" : "+v"(hi0), "+v"(hi1));
            u32x4v pw;
            pw.x = lo0; pw.y = hi0; pw.z = lo1; pw.w = hi1;
            pb[cp] = __builtin_bit_cast(bf16x8, pw);
        }
#undef SVAL

#pragma unroll
        for (int cp = 0; cp < 4; cp++) {
            bf16x8 v0 = *(const bf16x8*)&Vs[cur][kr0o + ((cp * 16 + hl * 8) ^ fsw)];
            bf16x8 v1 = *(const bf16x8*)&Vs[cur][kr1o + ((cp * 16 + hl * 8) ^ fsw)];
            acc0 = __builtin_amdgcn_mfma_f32_32x32x16_bf16(v0, pb[cp], acc0, 0, 0, 0);
            acc1 = __builtin_amdgcn_mfma_f32_32x32x16_bf16(v1, pb[cp], acc1, 0, 0, 0);
            accl = __builtin_amdgcn_mfma_f32_32x32x16_bf16(vOnes, pb[cp], accl, 0, 0, 0);
        }

        __syncthreads();
    }
#undef STAGE_DMA

    // ---- epilogue: normalize, write bf16 pre-swizzled (B,S,D) ----
    float inv = 1.f / accl[0];
    unsigned short* ob = Xb16 + ((size_t)b * S_ + q0 + q) * D_ + hh * DK_;
    const int rsw = q & 3;
#pragma unroll
    for (int b2 = 0; b2 < 4; b2++) {
        uint2 o0;
        o0.x = cvt_pk_bf16(acc0[4 * b2 + 0] * inv, acc0[4 * b2 + 1] * inv);
        o0.y = cvt_pk_bf16(acc0[4 * b2 + 2] * inv, acc0[4 * b2 + 3] * inv);
        *(uint2*)(ob + (((b2 ^ rsw) << 3) + 4 * hl)) = o0;
        uint2 o1;
        o1.x = cvt_pk_bf16(acc1[4 * b2 + 0] * inv, acc1[4 * b2 + 1] * inv);
        o1.y = cvt_pk_bf16(acc1[4 * b2 + 2] * inv, acc1[4 * b2 + 3] * inv);
        *(uint2*)(ob + 32 + (((b2 ^ rsw) << 3) + 4 * hl)) = o1;
    }
}

// ---------------- host launcher ----------------
extern "C" void kernel_launch(void* const* d_in, const int* in_sizes, int n_in,
                              void* d_out, int out_size, void* d_ws, size_t ws_size,
                              hipStream_t stream) {
    (void)in_sizes; (void)n_in; (void)out_size; (void)ws_size;

    const float* query = (const float*)d_in[0];
    const float* key_  = (const float*)d_in[1];
    const float* value = (const float*)d_in[2];
    const int*   mask  = (const int*)d_in[3];
    const float* Wq = (const float*)d_in[4];  const float* bq = (const float*)d_in[5];
    const float* Wk = (const float*)d_in[6];  const float* bk = (const float*)d_in[7];
    const float* Wv = (const float*)d_in[8];  const float* bv = (const float*)d_in[9];
    const float* Wo = (const float*)d_in[10]; const float* bo = (const float*)d_in[11];
    float* out = (float*)d_out;

    const size_t MD = (size_t)M_ * D_;     // 6,291,456
    const size_t DD = (size_t)D_ * D_;     // 589,824
    unsigned short* q16  = (unsigned short*)d_ws;
    unsigned short* k16  = q16 + MD;
    unsigned short* v16  = k16 + MD;
    unsigned short* Qb   = v16 + MD;
    unsigned short* Kb   = Qb + MD;
    unsigned short* VT   = Kb + MD;
    unsigned short* Xb16 = VT + MD;
    unsigned short* Wq16 = Xb16 + MD;
    unsigned short* Wk16 = Wq16 + DD;
    unsigned short* Wv16 = Wk16 + DD;
    unsigned short* Wo16 = Wv16 + DD;

    cvt_all<<<dim3(1024, 7), 256, 0, stream>>>(
        query, key_, value, Wq, Wk, Wv, Wo,
        q16, k16, v16, Wq16, Wk16, Wv16, Wo16);

    gemm_qkv<<<dim3(M_ / 128, D_ / 128, 3), 256, 0, stream>>>(
        q16, k16, v16, Wq16, Wk16, Wv16, bq, bk, bv, Qb, Kb, VT);

    attn_mfma<<<dim3((S_ / 128) * NBH_), 256, 0, stream>>>(Qb, Kb, VT, mask, Xb16);

    gemm_o<<<dim3(M_ / 128, D_ / 128), 256, 0, stream>>>(Xb16, Wo16, bo, out);
}